// Round 6
// baseline (299.886 us; speedup 1.0000x reference)
//
#include <hip/hip_runtime.h>
#include <hip/hip_bf16.h>
#include <math.h>

#define B_ 2
#define L_ 1024
#define D_ 1024
#define H_ 16

typedef short short8 __attribute__((ext_vector_type(8)));
typedef short short4v __attribute__((ext_vector_type(4)));
typedef float f32x4  __attribute__((ext_vector_type(4)));

__device__ __forceinline__ short f2bf(float f) {
  unsigned u = __float_as_uint(f);
  u += 0x7fff + ((u >> 16) & 1);          // RNE
  return (short)(u >> 16);
}
__device__ __forceinline__ float bf2f(short s) {
  return __uint_as_float(((unsigned)(unsigned short)s) << 16);
}
// P-tile XOR key (wave-private P buffer bank spread)
__device__ __forceinline__ int pkey(int row) {
  return (row & 7) ^ ((row & 8) >> 2);
}

// ---------------------------------------------------------------------------
// prep: (a) cast E,Ev,R -> bf16 contiguous; (b) transpose+cast 5 weights.
// ---------------------------------------------------------------------------
__global__ __launch_bounds__(256) void prep(
    const float* __restrict__ E, const float* __restrict__ Ev,
    const float* __restrict__ R,
    const float* __restrict__ W0, const float* __restrict__ W1,
    const float* __restrict__ W2, const float* __restrict__ W3,
    const float* __restrict__ W4,
    short* __restrict__ act, short* __restrict__ Wt) {
  __shared__ short t[64][65];
  const int tid = threadIdx.x;
  int bid = blockIdx.x;
  if (bid < 2560) {
    size_t i8 = ((size_t)bid * 256 + tid) * 8;
    const float* src; size_t off;
    if (i8 < 2097152)      { src = E;  off = i8; }
    else if (i8 < 4194304) { src = Ev; off = i8 - 2097152; }
    else                   { src = R;  off = i8 - 4194304; }
    float4 a = *(const float4*)&src[off];
    float4 b = *(const float4*)&src[off + 4];
    short8 v;
    v[0] = f2bf(a.x); v[1] = f2bf(a.y); v[2] = f2bf(a.z); v[3] = f2bf(a.w);
    v[4] = f2bf(b.x); v[5] = f2bf(b.y); v[6] = f2bf(b.z); v[7] = f2bf(b.w);
    *(short8*)&act[i8] = v;
    return;
  }
  bid -= 2560;
  const int z = bid >> 8, rem = bid & 255;
  const int by = rem >> 4, bx = rem & 15;
  const float* W = (z == 0) ? W0 : (z == 1) ? W1 : (z == 2) ? W2 : (z == 3) ? W3 : W4;
  short* Wtz = Wt + (size_t)z * D_ * D_;
  const int r0 = by * 64, c0 = bx * 64;
  #pragma unroll
  for (int i = 0; i < 4; ++i) {
    int idx = tid + i * 256;
    int r = idx >> 4, c4 = (idx & 15) * 4;
    float4 v = *(const float4*)&W[(size_t)(r0 + r) * D_ + c0 + c4];
    t[c4 + 0][r] = f2bf(v.x); t[c4 + 1][r] = f2bf(v.y);
    t[c4 + 2][r] = f2bf(v.z); t[c4 + 3][r] = f2bf(v.w);
  }
  __syncthreads();
  #pragma unroll
  for (int i = 0; i < 2; ++i) {
    int idx = tid + i * 256;
    int rr = idx >> 3, cc = (idx & 7) * 8;
    short8 o;
    #pragma unroll
    for (int e = 0; e < 8; ++e) o[e] = t[rr][cc + e];
    *(short8*)&Wtz[(size_t)(c0 + rr) * D_ + r0 + cc] = o;
  }
}

// ---------------------------------------------------------------------------
// Barrier-free direct-global bf16 GEMM. 1 wave per block; wave tile 32x64.
// C[M,1024] = A[M,1024] @ Bt[1024,1024]^T. A/B fragments read straight from
// global (L2-resident operands; no LDS, no __syncthreads).
// OUT: 0 = bf16 row-major, 1 = f32 row-major, 2 = bf16 transposed per-head
//      (vt[((b*16+h)*64+d)*1024 + j], for attention PV B-operand).
// ---------------------------------------------------------------------------
template<int OUT>
__device__ __forceinline__ void mmd(const short* __restrict__ A,
                                    const short* __restrict__ Bt,
                                    void* __restrict__ Cp,
                                    int bx, int by) {
  const int l = threadIdx.x & 63;
  const int row0 = by * 32, col0 = bx * 64;
  const f32x4 fz = {0.f, 0.f, 0.f, 0.f};

  f32x4 acc[2][4];
  #pragma unroll
  for (int i = 0; i < 2; ++i)
    #pragma unroll
    for (int j = 0; j < 4; ++j) acc[i][j] = fz;

  const short* Ap = &A[(size_t)(row0 + (l & 15)) * 1024 + (l >> 4) * 8];
  const short* Bp = &Bt[(size_t)(col0 + (l & 15)) * 1024 + (l >> 4) * 8];

  #pragma unroll 2
  for (int kk = 0; kk < 32; ++kk) {
    const int ko = kk * 32;
    short8 a0 = *(const short8*)(Ap + ko);
    short8 a1 = *(const short8*)(Ap + 16384 + ko);
    short8 b0 = *(const short8*)(Bp + ko);
    short8 b1 = *(const short8*)(Bp + 16384 + ko);
    short8 b2 = *(const short8*)(Bp + 32768 + ko);
    short8 b3 = *(const short8*)(Bp + 49152 + ko);
    acc[0][0] = __builtin_amdgcn_mfma_f32_16x16x32_bf16(a0, b0, acc[0][0], 0, 0, 0);
    acc[0][1] = __builtin_amdgcn_mfma_f32_16x16x32_bf16(a0, b1, acc[0][1], 0, 0, 0);
    acc[0][2] = __builtin_amdgcn_mfma_f32_16x16x32_bf16(a0, b2, acc[0][2], 0, 0, 0);
    acc[0][3] = __builtin_amdgcn_mfma_f32_16x16x32_bf16(a0, b3, acc[0][3], 0, 0, 0);
    acc[1][0] = __builtin_amdgcn_mfma_f32_16x16x32_bf16(a1, b0, acc[1][0], 0, 0, 0);
    acc[1][1] = __builtin_amdgcn_mfma_f32_16x16x32_bf16(a1, b1, acc[1][1], 0, 0, 0);
    acc[1][2] = __builtin_amdgcn_mfma_f32_16x16x32_bf16(a1, b2, acc[1][2], 0, 0, 0);
    acc[1][3] = __builtin_amdgcn_mfma_f32_16x16x32_bf16(a1, b3, acc[1][3], 0, 0, 0);
  }

  #pragma unroll
  for (int mf = 0; mf < 2; ++mf)
    #pragma unroll
    for (int nf = 0; nf < 4; ++nf) {
      if (OUT == 2) {
        // transposed per-head store: 4 consecutive j -> short4
        int tok = row0 + mf * 16 + (l >> 4) * 4;
        int col = col0 + nf * 16 + (l & 15);
        int bb = tok >> 10, j = tok & 1023;
        int h = col >> 6, d = col & 63;
        short4v o;
        #pragma unroll
        for (int r = 0; r < 4; ++r) o[r] = f2bf(acc[mf][nf][r]);
        *(short4v*)&((short*)Cp)[((size_t)((bb * H_ + h) * 64 + d)) * 1024 + j] = o;
      } else {
        #pragma unroll
        for (int r = 0; r < 4; ++r) {
          int row = row0 + mf * 16 + (l >> 4) * 4 + r;
          int col = col0 + nf * 16 + (l & 15);
          if (OUT == 1) ((float*)Cp)[(size_t)row * 1024 + col] = acc[mf][nf][r];
          else          ((short*)Cp)[(size_t)row * 1024 + col] = f2bf(acc[mf][nf][r]);
        }
      }
    }
}

// z=0: q=Eb@Wq ; z=1: k=Evb@Wke ; z=2: vt=(Evb@Wv)^T ; z=3: Qp=Rb@Wkr.
__global__ __launch_bounds__(64) void proj_g(
    const short* __restrict__ Eb, const short* __restrict__ Evb,
    const short* __restrict__ Rb, const short* __restrict__ Wt,
    short* __restrict__ qb, short* __restrict__ kb,
    short* __restrict__ vt, short* __restrict__ Qpb) {
  const int z = blockIdx.z;
  const int bx = blockIdx.x & 15, by = blockIdx.x >> 4;
  const size_t MM = (size_t)D_ * D_;
  const short* A; const short* Bt; short* C; int M;
  if (z == 0)      { A = Eb;  Bt = Wt;          C = qb;  M = B_ * L_; }
  else if (z == 1) { A = Evb; Bt = Wt + MM;     C = kb;  M = B_ * L_; }
  else if (z == 2) { A = Evb; Bt = Wt + 3 * MM; C = vt;  M = B_ * L_; }
  else             { A = Rb;  Bt = Wt + 2 * MM; C = Qpb; M = L_;      }
  if (by * 32 >= M) return;
  if (z == 2) mmd<2>(A, Bt, C, bx, by);
  else        mmd<0>(A, Bt, C, bx, by);
}

__global__ __launch_bounds__(64) void out_g(
    const short* __restrict__ Ob, const short* __restrict__ Wot,
    float* __restrict__ proj) {
  mmd<1>(Ob, Wot, proj, blockIdx.x & 15, blockIdx.x >> 4);
}

// ---------------------------------------------------------------------------
// Barrier-free MFMA attention. 1 wave per 16 q-rows of one (b,h).
// S = (q+cb).k_j + mask * (q+pb).Qp[L-1-i+j]; full-row softmax; PV from
// pre-transposed vt. All MFMA operands except P read directly from global
// (L2-resident). LDS: wave-private 2.6KB P/Pb buffer only. No __syncthreads.
// ---------------------------------------------------------------------------
__global__ __launch_bounds__(64) void attn_d(
    const short* __restrict__ qb, const short* __restrict__ kb,
    const short* __restrict__ vt, const short* __restrict__ Qpb,
    const float* __restrict__ cb, const float* __restrict__ pb,
    short* __restrict__ Ob) {
  __shared__ short pbs[1312];     // Pb[16][82] | P[16][64] (time-overlaid)

  const int l = threadIdx.x & 63;
  const int hl = blockIdx.x & 31;        // head fastest -> XCD L2 locality
  const int it = blockIdx.x >> 5;        // 0..63
  const int b = hl >> 4, hh = hl & 15;
  const int i0 = it * 16;
  const f32x4 fz = {0.f, 0.f, 0.f, 0.f};

  // A-fragments in registers: aqc = bf16(q+cb), aqp = bf16(q+pb)
  short8 aqc[2], aqp[2];
  {
    const size_t qoff = (size_t)(b * L_ + i0 + (l & 15)) * D_ + hh * 64 + (l >> 4) * 8;
    #pragma unroll
    for (int kf = 0; kf < 2; ++kf) {
      short8 qv = *(const short8*)&qb[qoff + kf * 32];
      f32x4 c0 = *(const f32x4*)&cb[hh * 64 + kf * 32 + (l >> 4) * 8];
      f32x4 c1 = *(const f32x4*)&cb[hh * 64 + kf * 32 + (l >> 4) * 8 + 4];
      f32x4 p0 = *(const f32x4*)&pb[hh * 64 + kf * 32 + (l >> 4) * 8];
      f32x4 p1 = *(const f32x4*)&pb[hh * 64 + kf * 32 + (l >> 4) * 8 + 4];
      #pragma unroll
      for (int e = 0; e < 8; ++e) {
        float q = bf2f(qv[e]);
        float cc = (e < 4) ? c0[e] : c1[e - 4];
        float pp = (e < 4) ? p0[e] : p1[e - 4];
        aqc[kf][e] = f2bf(q + cc);
        aqp[kf][e] = f2bf(q + pp);
      }
    }
  }

  const short* kbase  = &kb[(size_t)(b * L_) * D_ + hh * 64 + (l >> 4) * 8];
  const short* vtbase = &vt[(size_t)((b * H_ + hh) * 64) * 1024 + (l >> 4) * 8];

  float mrow[4], lrow[4];
  f32x4 oacc[4];
  #pragma unroll
  for (int r = 0; r < 4; ++r) { mrow[r] = -3.0e38f; lrow[r] = 0.f; }
  #pragma unroll
  for (int nf = 0; nf < 4; ++nf) oacc[nf] = fz;

  for (int jt = 0; jt < 16; ++jt) {
    const int j0 = jt * 64;
    const int dth = i0 - j0;             // j<=i  <=>  rj <= ri + dth
    const bool pos = (dth >= -15);
    const int mb = L_ - 16 - dth;        // positional window base

    // ---- QK^T: S += (q+cb).k  (B-frags direct from global) ----
    f32x4 sac[4];
    #pragma unroll
    for (int nf = 0; nf < 4; ++nf) sac[nf] = fz;
    __builtin_amdgcn_s_setprio(1);
    #pragma unroll
    for (int kf = 0; kf < 2; ++kf) {
      #pragma unroll
      for (int nf = 0; nf < 4; ++nf) {
        short8 bk = *(const short8*)&kbase[(size_t)(j0 + nf * 16 + (l & 15)) * D_ + kf * 32];
        sac[nf] = __builtin_amdgcn_mfma_f32_16x16x32_bf16(aqc[kf], bk, sac[nf], 0, 0, 0);
      }
    }
    __builtin_amdgcn_s_setprio(0);

    if (pos) {
      // ---- positional GEMM: (q+pb).Qp over 80-col window ----
      f32x4 pacc[5];
      #pragma unroll
      for (int u = 0; u < 5; ++u) pacc[u] = fz;
      __builtin_amdgcn_s_setprio(1);
      #pragma unroll
      for (int kf = 0; kf < 2; ++kf) {
        #pragma unroll
        for (int u = 0; u < 5; ++u) {
          int m = mb + u * 16 + (l & 15);
          m = (m < L_) ? m : (L_ - 1);   // clamped rows are masked below
          short8 bw = *(const short8*)&Qpb[(size_t)m * D_ + hh * 64 + kf * 32 + (l >> 4) * 8];
          pacc[u] = __builtin_amdgcn_mfma_f32_16x16x32_bf16(aqp[kf], bw, pacc[u], 0, 0, 0);
        }
      }
      __builtin_amdgcn_s_setprio(0);
      // Pb[ri][cu] in C-layout
      #pragma unroll
      for (int u = 0; u < 5; ++u)
        #pragma unroll
        for (int r = 0; r < 4; ++r) {
          int row = (l >> 4) * 4 + r;
          pbs[row * 82 + u * 16 + (l & 15)] = f2bf(pacc[u][r]);
        }
      // shifted gather: S[ri][rj] += Pb[ri][15-ri+rj] where j<=i
      #pragma unroll
      for (int nf = 0; nf < 4; ++nf)
        #pragma unroll
        for (int r = 0; r < 4; ++r) {
          int ris = (l >> 4) * 4 + r;
          int rj = nf * 16 + (l & 15);
          if (rj <= ris + dth)
            sac[nf][r] += bf2f(pbs[ris * 82 + (15 - ris + rj)]);
        }
    }

    // ---- online softmax (16-lane row groups) ----
    #pragma unroll
    for (int r = 0; r < 4; ++r) {
      float mx = fmaxf(fmaxf(sac[0][r], sac[1][r]), fmaxf(sac[2][r], sac[3][r]));
      #pragma unroll
      for (int off = 1; off < 16; off <<= 1)
        mx = fmaxf(mx, __shfl_xor(mx, off, 64));
      float mn = fmaxf(mrow[r], mx);
      float sc = __expf(mrow[r] - mn);
      mrow[r] = mn;
      float ls = 0.f;
      #pragma unroll
      for (int nf = 0; nf < 4; ++nf) {
        float p = __expf(sac[nf][r] - mn);
        sac[nf][r] = p;
        ls += p;
      }
      #pragma unroll
      for (int off = 1; off < 16; off <<= 1)
        ls += __shfl_xor(ls, off, 64);
      lrow[r] = lrow[r] * sc + ls;
      #pragma unroll
      for (int nf = 0; nf < 4; ++nf) oacc[nf][r] *= sc;
    }

    // ---- P -> bf16 LDS (overlays Pb; same-wave in-order DS) ----
    #pragma unroll
    for (int nf = 0; nf < 4; ++nf)
      #pragma unroll
      for (int r = 0; r < 4; ++r) {
        int row = (l >> 4) * 4 + r;
        int col = nf * 16 + (l & 15);
        pbs[row * 64 + (((col >> 3) ^ pkey(row)) << 3) + (col & 7)] = f2bf(sac[nf][r]);
      }

    // ---- PV: B-frags from pre-transposed vt (direct global) ----
    __builtin_amdgcn_s_setprio(1);
    #pragma unroll
    for (int kf = 0; kf < 2; ++kf) {
      int prow = l & 15;
      short8 ap = *(const short8*)&pbs[prow * 64 + (((kf * 4 + (l >> 4)) ^ pkey(prow)) << 3)];
      #pragma unroll
      for (int nf = 0; nf < 4; ++nf) {
        short8 bv = *(const short8*)&vtbase[(size_t)(nf * 16 + (l & 15)) * 1024 + j0 + kf * 32];
        oacc[nf] = __builtin_amdgcn_mfma_f32_16x16x32_bf16(ap, bv, oacc[nf], 0, 0, 0);
      }
    }
    __builtin_amdgcn_s_setprio(0);
  }

  #pragma unroll
  for (int r = 0; r < 4; ++r) {
    float inv = 1.f / lrow[r];
    #pragma unroll
    for (int nf = 0; nf < 4; ++nf) {
      int row = i0 + (l >> 4) * 4 + r;
      int col = hh * 64 + nf * 16 + (l & 15);
      Ob[(size_t)(b * L_ + row) * D_ + col] = f2bf(oacc[nf][r] * inv);
    }
  }
}

// ---------------------------------------------------------------------------
// res = Ev + proj + Wo_b; LayerNorm * g + b. One block per row.
// ---------------------------------------------------------------------------
__global__ __launch_bounds__(256) void ln_kernel(
    const float* __restrict__ Ev, const float* __restrict__ proj,
    const float* __restrict__ Wo_b, const float* __restrict__ g,
    const float* __restrict__ beta, float* __restrict__ out) {
  const int row = blockIdx.x;
  __shared__ float red[8];
  const int tid = threadIdx.x;
  const int d = tid * 4;

  float4 e  = *(const float4*)&Ev[(size_t)row * D_ + d];
  float4 p  = *(const float4*)&proj[(size_t)row * D_ + d];
  float4 wb = *(const float4*)&Wo_b[d];
  float4 rr = { e.x + p.x + wb.x, e.y + p.y + wb.y,
                e.z + p.z + wb.z, e.w + p.w + wb.w };
  float sum = rr.x + rr.y + rr.z + rr.w;
  float sq  = rr.x * rr.x + rr.y * rr.y + rr.z * rr.z + rr.w * rr.w;

  #pragma unroll
  for (int off = 1; off < 64; off <<= 1) {
    sum += __shfl_xor(sum, off, 64);
    sq  += __shfl_xor(sq,  off, 64);
  }
  const int wid = tid >> 6;
  if ((tid & 63) == 0) { red[wid * 2] = sum; red[wid * 2 + 1] = sq; }
  __syncthreads();
  sum = red[0] + red[2] + red[4] + red[6];
  sq  = red[1] + red[3] + red[5] + red[7];

  const float mu   = sum * (1.f / (float)D_);
  const float var  = sq * (1.f / (float)D_) - mu * mu;
  const float rstd = rsqrtf(var + 1e-5f);

  float4 gg = *(const float4*)&g[d];
  float4 bb = *(const float4*)&beta[d];
  float4 o = { (rr.x - mu) * rstd * gg.x + bb.x,
               (rr.y - mu) * rstd * gg.y + bb.y,
               (rr.z - mu) * rstd * gg.z + bb.z,
               (rr.w - mu) * rstd * gg.w + bb.w };
  *(float4*)&out[(size_t)row * D_ + d] = o;
}

// ---------------------------------------------------------------------------
extern "C" void kernel_launch(void* const* d_in, const int* in_sizes, int n_in,
                              void* d_out, int out_size, void* d_ws, size_t ws_size,
                              hipStream_t stream) {
  const float* E    = (const float*)d_in[0];
  const float* Ev   = (const float*)d_in[1];
  const float* R    = (const float*)d_in[2];
  const float* Wq   = (const float*)d_in[3];
  const float* Wke  = (const float*)d_in[4];
  const float* Wkr  = (const float*)d_in[5];
  const float* Wv   = (const float*)d_in[6];
  const float* cb   = (const float*)d_in[7];
  const float* pb   = (const float*)d_in[8];
  const float* Wo_w = (const float*)d_in[9];
  const float* Wo_b = (const float*)d_in[10];
  const float* ln_g = (const float*)d_in[11];
  const float* ln_b = (const float*)d_in[12];
  float* out = (float*)d_out;

  // ws (shorts): Eb 2M | Evb 2M | Rb 1M | qb 2M | kb 2M | vt 2M | Qpb 1M |
  // Wt 5M | Ob 2M = 19M shorts = 38MB. proj fp32 overlays Eb+Evb (dead
  // after proj_g).
  short* ws   = (short*)d_ws;
  short* Eb   = ws;
  short* Evb  = ws + 2097152;
  short* Rb   = ws + 4194304;
  short* qb   = ws + 5242880;
  short* kb   = ws + 7340032;
  short* vt   = ws + 9437184;
  short* Qpb  = ws + 11534336;
  short* Wt   = ws + 12582912;
  short* Ob   = ws + 17825792;
  float* proj = (float*)Eb;

  // 1) prep: cast activations + transpose/cast weights
  prep<<<3840, 256, 0, stream>>>(E, Ev, R, Wq, Wke, Wkr, Wv, Wo_w, Eb, Wt);

  // 2) projections -> bf16 q, k, vt(transposed), Qp  (barrier-free direct GEMM)
  proj_g<<<dim3(1024, 1, 4), 64, 0, stream>>>(Eb, Evb, Rb, Wt, qb, kb, vt, Qpb);

  // 3) attention -> bf16 O (barrier-free, biases folded into A-fragments)
  attn_d<<<2048, 64, 0, stream>>>(qb, kb, vt, Qpb, cb, pb, Ob);

  // 4) output projection -> fp32 proj
  out_g<<<1024, 64, 0, stream>>>(Ob, Wt + 4 * (size_t)D_ * D_, proj);

  // 5) residual + LayerNorm
  ln_kernel<<<B_ * L_, 256, 0, stream>>>(Ev, proj, Wo_b, ln_g, ln_b, out);
}

// Round 7
// 240.677 us; speedup vs baseline: 1.2460x; 1.2460x over previous
//
#include <hip/hip_runtime.h>
#include <hip/hip_bf16.h>
#include <math.h>

#define B_ 2
#define L_ 1024
#define D_ 1024
#define H_ 16

typedef short short8 __attribute__((ext_vector_type(8)));
typedef short short4v __attribute__((ext_vector_type(4)));
typedef float f32x4  __attribute__((ext_vector_type(4)));

__device__ __forceinline__ short f2bf(float f) {
  unsigned u = __float_as_uint(f);
  u += 0x7fff + ((u >> 16) & 1);          // RNE
  return (short)(u >> 16);
}
__device__ __forceinline__ float bf2f(short s) {
  return __uint_as_float(((unsigned)(unsigned short)s) << 16);
}
// XOR-swizzled LDS index (shorts) for [rows][64] bf16 tiles (16B slots).
__device__ __forceinline__ int swz(int row, int slot) {
  return row * 64 + (((slot ^ row) & 7) << 3);
}
// P-tile XOR key (wave-private P buffer bank spread)
__device__ __forceinline__ int pkey(int row) {
  return (row & 7) ^ ((row & 8) >> 2);
}
// global -> LDS direct (16B/lane; LDS dest = wave-uniform base + lane*16)
__device__ __forceinline__ void glds16(const void* g, void* l) {
  __builtin_amdgcn_global_load_lds((const __attribute__((address_space(1))) void*)g,
                                   (__attribute__((address_space(3))) void*)l, 16, 0, 0);
}

// ---------------------------------------------------------------------------
// prep: (a) cast E,Ev,R -> bf16 contiguous; (b) transpose+cast 5 weights.
// ---------------------------------------------------------------------------
__global__ __launch_bounds__(256) void prep(
    const float* __restrict__ E, const float* __restrict__ Ev,
    const float* __restrict__ R,
    const float* __restrict__ W0, const float* __restrict__ W1,
    const float* __restrict__ W2, const float* __restrict__ W3,
    const float* __restrict__ W4,
    short* __restrict__ act, short* __restrict__ Wt) {
  __shared__ short t[64][65];
  const int tid = threadIdx.x;
  int bid = blockIdx.x;
  if (bid < 2560) {
    size_t i8 = ((size_t)bid * 256 + tid) * 8;
    const float* src; size_t off;
    if (i8 < 2097152)      { src = E;  off = i8; }
    else if (i8 < 4194304) { src = Ev; off = i8 - 2097152; }
    else                   { src = R;  off = i8 - 4194304; }
    float4 a = *(const float4*)&src[off];
    float4 b = *(const float4*)&src[off + 4];
    short8 v;
    v[0] = f2bf(a.x); v[1] = f2bf(a.y); v[2] = f2bf(a.z); v[3] = f2bf(a.w);
    v[4] = f2bf(b.x); v[5] = f2bf(b.y); v[6] = f2bf(b.z); v[7] = f2bf(b.w);
    *(short8*)&act[i8] = v;
    return;
  }
  bid -= 2560;
  const int z = bid >> 8, rem = bid & 255;
  const int by = rem >> 4, bx = rem & 15;
  const float* W = (z == 0) ? W0 : (z == 1) ? W1 : (z == 2) ? W2 : (z == 3) ? W3 : W4;
  short* Wtz = Wt + (size_t)z * D_ * D_;
  const int r0 = by * 64, c0 = bx * 64;
  #pragma unroll
  for (int i = 0; i < 4; ++i) {
    int idx = tid + i * 256;
    int r = idx >> 4, c4 = (idx & 15) * 4;
    float4 v = *(const float4*)&W[(size_t)(r0 + r) * D_ + c0 + c4];
    t[c4 + 0][r] = f2bf(v.x); t[c4 + 1][r] = f2bf(v.y);
    t[c4 + 2][r] = f2bf(v.z); t[c4 + 3][r] = f2bf(v.w);
  }
  __syncthreads();
  #pragma unroll
  for (int i = 0; i < 2; ++i) {
    int idx = tid + i * 256;
    int rr = idx >> 3, cc = (idx & 7) * 8;
    short8 o;
    #pragma unroll
    for (int e = 0; e < 8; ++e) o[e] = t[rr][cc + e];
    *(short8*)&Wtz[(size_t)(c0 + rr) * D_ + r0 + cc] = o;
  }
}

// ---------------------------------------------------------------------------
// Double-buffered bf16 MFMA GEMM: C[M,1024] = A[M,1024] @ Bt[1024,1024]^T.
// Tile 64 x (NF*32), BK=64, 4 waves. STAGE(t+1) issued BEFORE COMPUTE(t)
// (T3-minimum): loads fly under MFMA; one __syncthreads per K-step. Static
// As0/As1 buffers so compiler can prove no-alias (no early vmcnt drain).
// OUT: 0 = bf16 row-major, 1 = f32 row-major, 2 = bf16 per-head transposed
//      vt[((b*16+h)*64+d)*1024 + j].
// ---------------------------------------------------------------------------
template<int NF, int OUT>
__device__ __forceinline__ void mm_db(const short* __restrict__ A,
                                      const short* __restrict__ Bt,
                                      void* __restrict__ Cp,
                                      int bx, int by) {
  __shared__ short As0[4096], As1[4096];
  __shared__ short Bs0[NF * 2048], Bs1[NF * 2048];
  const int tid = threadIdx.x;
  const int l = tid & 63, w = tid >> 6;
  const int row0 = by * 64, col0 = bx * (NF * 32);
  const int wm = (w >> 1) * 32, wn = (w & 1) * (NF * 16);
  const int lr = l >> 3;                 // row within 8-row chunk
  const int lc = ((l & 7) ^ lr) * 8;     // inverse-swizzled source slot
  const f32x4 fz = {0.f, 0.f, 0.f, 0.f};

  f32x4 acc[2][NF];
  #pragma unroll
  for (int i = 0; i < 2; ++i)
    #pragma unroll
    for (int j = 0; j < NF; ++j) acc[i][j] = fz;

  auto STAGE = [&](short* AsD, short* BsD, int k0) {
    #pragma unroll
    for (int c = 0; c < 2; ++c) {
      int ch = w * 2 + c;
      glds16(&A[(size_t)(row0 + ch * 8 + lr) * 1024 + k0 + lc], &AsD[ch * 512]);
    }
    #pragma unroll
    for (int c = 0; c < NF; ++c) {
      int ch = w * NF + c;
      glds16(&Bt[(size_t)(col0 + ch * 8 + lr) * 1024 + k0 + lc], &BsD[ch * 512]);
    }
  };
  auto COMP = [&](const short* AsS, const short* BsS) {
    #pragma unroll
    for (int kf = 0; kf < 2; ++kf) {
      const int slot = kf * 4 + (l >> 4);
      short8 a[2], bfr[NF];
      #pragma unroll
      for (int mf = 0; mf < 2; ++mf)
        a[mf] = *(const short8*)&AsS[swz(wm + mf * 16 + (l & 15), slot)];
      #pragma unroll
      for (int nf = 0; nf < NF; ++nf)
        bfr[nf] = *(const short8*)&BsS[swz(wn + nf * 16 + (l & 15), slot)];
      #pragma unroll
      for (int mf = 0; mf < 2; ++mf)
        #pragma unroll
        for (int nf = 0; nf < NF; ++nf)
          acc[mf][nf] = __builtin_amdgcn_mfma_f32_16x16x32_bf16(a[mf], bfr[nf], acc[mf][nf], 0, 0, 0);
    }
  };

  STAGE(As0, Bs0, 0);
  __syncthreads();
  for (int t = 0; t < 16; t += 2) {
    if (t + 1 < 16) STAGE(As1, Bs1, (t + 1) * 64);
    COMP(As0, Bs0);
    __syncthreads();                      // As1 ready; As0 free to overwrite
    if (t + 2 < 16) STAGE(As0, Bs0, (t + 2) * 64);
    COMP(As1, Bs1);
    __syncthreads();                      // As0 ready; As1 free
  }

  #pragma unroll
  for (int mf = 0; mf < 2; ++mf)
    #pragma unroll
    for (int nf = 0; nf < NF; ++nf) {
      if (OUT == 2) {
        int tok = row0 + wm + mf * 16 + (l >> 4) * 4;
        int col = col0 + wn + nf * 16 + (l & 15);
        int bb = tok >> 10, j = tok & 1023;
        int h = col >> 6, d = col & 63;
        short4v o;
        #pragma unroll
        for (int r = 0; r < 4; ++r) o[r] = f2bf(acc[mf][nf][r]);
        *(short4v*)&((short*)Cp)[((size_t)((bb * H_ + h) * 64 + d)) * 1024 + j] = o;
      } else {
        #pragma unroll
        for (int r = 0; r < 4; ++r) {
          int row = row0 + wm + mf * 16 + (l >> 4) * 4 + r;
          int col = col0 + wn + nf * 16 + (l & 15);
          if (OUT == 1) ((float*)Cp)[(size_t)row * 1024 + col] = acc[mf][nf][r];
          else          ((short*)Cp)[(size_t)row * 1024 + col] = f2bf(acc[mf][nf][r]);
        }
      }
    }
}

// z=0: q=Eb@Wq ; z=1: k=Evb@Wke ; z=2: vt=(Evb@Wv)^T ; z=3: Qp=Rb@Wkr.
__global__ __launch_bounds__(256) void proj_g(
    const short* __restrict__ Eb, const short* __restrict__ Evb,
    const short* __restrict__ Rb, const short* __restrict__ Wt,
    short* __restrict__ qb, short* __restrict__ kb,
    short* __restrict__ vt, short* __restrict__ Qpb) {
  const int z = blockIdx.z;
  const size_t MM = (size_t)D_ * D_;
  const short* A; const short* Bt; short* C; int M;
  if (z == 0)      { A = Eb;  Bt = Wt;          C = qb;  M = B_ * L_; }
  else if (z == 1) { A = Evb; Bt = Wt + MM;     C = kb;  M = B_ * L_; }
  else if (z == 2) { A = Evb; Bt = Wt + 3 * MM; C = vt;  M = B_ * L_; }
  else             { A = Rb;  Bt = Wt + 2 * MM; C = Qpb; M = L_;      }
  if ((int)blockIdx.y * 64 >= M) return;
  if (z == 2) mm_db<2, 2>(A, Bt, C, blockIdx.x, blockIdx.y);
  else        mm_db<2, 0>(A, Bt, C, blockIdx.x, blockIdx.y);
}

__global__ __launch_bounds__(256) void out_g(
    const short* __restrict__ Ob, const short* __restrict__ Wot,
    float* __restrict__ proj) {
  mm_db<2, 1>(Ob, Wot, proj, blockIdx.x, blockIdx.y);
}

// ---------------------------------------------------------------------------
// Barrier-free MFMA attention with register prefetch (T14). 1 wave per 16
// q-rows of one (b,h). All MFMA operands direct from global (L2-resident),
// loaded >= 1 compute-phase before use:
//   - bv (V, tile t): issued at tile top, used after softmax
//   - bk/bw (K/window, tile t+1): issued after tile t's score MFMAs,
//     used next iteration (fly under softmax+pack+PV)
// S = (q+cb).k_j + mask * (q+pb).Qp[L-1-i+j]; full-row softmax.
// ---------------------------------------------------------------------------
__global__ __launch_bounds__(64) void attn_d(
    const short* __restrict__ qb, const short* __restrict__ kb,
    const short* __restrict__ vt, const short* __restrict__ Qpb,
    const float* __restrict__ cb, const float* __restrict__ pb,
    short* __restrict__ Ob) {
  __shared__ short pbs[1312];     // Pb[16][82] | P[16][64] (time-overlaid)

  const int l = threadIdx.x & 63;
  const int hl = blockIdx.x & 31;        // head fastest: XCD x serves heads {x,x+8,x+16,x+24}
  const int it = blockIdx.x >> 5;        // 0..63
  const int b = hl >> 4, hh = hl & 15;
  const int i0 = it * 16;
  const f32x4 fz = {0.f, 0.f, 0.f, 0.f};

  // A-fragments in registers: aqc = bf16(q+cb), aqp = bf16(q+pb)
  short8 aqc[2], aqp[2];
  {
    const size_t qoff = (size_t)(b * L_ + i0 + (l & 15)) * D_ + hh * 64 + (l >> 4) * 8;
    #pragma unroll
    for (int kf = 0; kf < 2; ++kf) {
      short8 qv = *(const short8*)&qb[qoff + kf * 32];
      f32x4 c0 = *(const f32x4*)&cb[hh * 64 + kf * 32 + (l >> 4) * 8];
      f32x4 c1 = *(const f32x4*)&cb[hh * 64 + kf * 32 + (l >> 4) * 8 + 4];
      f32x4 p0 = *(const f32x4*)&pb[hh * 64 + kf * 32 + (l >> 4) * 8];
      f32x4 p1 = *(const f32x4*)&pb[hh * 64 + kf * 32 + (l >> 4) * 8 + 4];
      #pragma unroll
      for (int e = 0; e < 8; ++e) {
        float q = bf2f(qv[e]);
        float cc = (e < 4) ? c0[e] : c1[e - 4];
        float pp = (e < 4) ? p0[e] : p1[e - 4];
        aqc[kf][e] = f2bf(q + cc);
        aqp[kf][e] = f2bf(q + pp);
      }
    }
  }

  const short* kbase  = &kb[(size_t)(b * L_) * D_ + hh * 64 + (l >> 4) * 8];
  const short* vtbase = &vt[(size_t)((b * H_ + hh) * 64) * 1024 + (l >> 4) * 8];
  const short* wbase  = &Qpb[hh * 64 + (l >> 4) * 8];

  short8 bk[2][4], bw[2][5], bv[2][4];

  auto LK = [&](int jt) {
    const int j0 = jt * 64;
    #pragma unroll
    for (int kf = 0; kf < 2; ++kf)
      #pragma unroll
      for (int nf = 0; nf < 4; ++nf)
        bk[kf][nf] = *(const short8*)&kbase[(size_t)(j0 + nf * 16 + (l & 15)) * D_ + kf * 32];
  };
  auto LW = [&](int jt) {
    const int mb = L_ - 16 - (i0 - jt * 64);
    #pragma unroll
    for (int kf = 0; kf < 2; ++kf)
      #pragma unroll
      for (int u = 0; u < 5; ++u) {
        int m = mb + u * 16 + (l & 15);
        m = (m < L_) ? m : (L_ - 1);     // clamped rows masked in gather
        bw[kf][u] = *(const short8*)&wbase[(size_t)m * D_ + kf * 32];
      }
  };
  auto LV = [&](int jt) {
    const int j0 = jt * 64;
    #pragma unroll
    for (int kf = 0; kf < 2; ++kf)
      #pragma unroll
      for (int nf = 0; nf < 4; ++nf)
        bv[kf][nf] = *(const short8*)&vtbase[(size_t)(nf * 16 + (l & 15)) * 1024 + j0 + kf * 32];
  };

  LK(0); LW(0);                          // jt=0 is always pos (dth = i0 >= 0)

  float mrow[4], lrow[4];
  f32x4 oacc[4];
  #pragma unroll
  for (int r = 0; r < 4; ++r) { mrow[r] = -3.0e38f; lrow[r] = 0.f; }
  #pragma unroll
  for (int nf = 0; nf < 4; ++nf) oacc[nf] = fz;

  for (int jt = 0; jt < 16; ++jt) {
    const int dth = i0 - jt * 64;        // j<=i  <=>  rj <= ri + dth
    const bool pos = (dth >= -15);

    LV(jt);                              // V flies under QK/pos/softmax

    // ---- QK^T from prefetched bk ----
    f32x4 sac[4];
    #pragma unroll
    for (int nf = 0; nf < 4; ++nf) sac[nf] = fz;
    __builtin_amdgcn_s_setprio(1);
    #pragma unroll
    for (int kf = 0; kf < 2; ++kf)
      #pragma unroll
      for (int nf = 0; nf < 4; ++nf)
        sac[nf] = __builtin_amdgcn_mfma_f32_16x16x32_bf16(aqc[kf], bk[kf][nf], sac[nf], 0, 0, 0);
    __builtin_amdgcn_s_setprio(0);

    if (pos) {
      // ---- positional GEMM from prefetched bw ----
      f32x4 pacc[5];
      #pragma unroll
      for (int u = 0; u < 5; ++u) pacc[u] = fz;
      __builtin_amdgcn_s_setprio(1);
      #pragma unroll
      for (int kf = 0; kf < 2; ++kf)
        #pragma unroll
        for (int u = 0; u < 5; ++u)
          pacc[u] = __builtin_amdgcn_mfma_f32_16x16x32_bf16(aqp[kf], bw[kf][u], pacc[u], 0, 0, 0);
      __builtin_amdgcn_s_setprio(0);
      #pragma unroll
      for (int u = 0; u < 5; ++u)
        #pragma unroll
        for (int r = 0; r < 4; ++r) {
          int row = (l >> 4) * 4 + r;
          pbs[row * 82 + u * 16 + (l & 15)] = f2bf(pacc[u][r]);
        }
    }

    // ---- prefetch next tile's K / window (bk/bw dead after MFMAs above) ----
    if (jt < 15) {
      LK(jt + 1);
      if (dth - 64 >= -15) LW(jt + 1);
    }

    if (pos) {
      // shifted gather: S[ri][rj] += Pb[ri][15-ri+rj] where j<=i
      #pragma unroll
      for (int nf = 0; nf < 4; ++nf)
        #pragma unroll
        for (int r = 0; r < 4; ++r) {
          int ris = (l >> 4) * 4 + r;
          int rj = nf * 16 + (l & 15);
          if (rj <= ris + dth)
            sac[nf][r] += bf2f(pbs[ris * 82 + (15 - ris + rj)]);
        }
    }

    // ---- online softmax (16-lane row groups) ----
    #pragma unroll
    for (int r = 0; r < 4; ++r) {
      float mx = fmaxf(fmaxf(sac[0][r], sac[1][r]), fmaxf(sac[2][r], sac[3][r]));
      #pragma unroll
      for (int off = 1; off < 16; off <<= 1)
        mx = fmaxf(mx, __shfl_xor(mx, off, 64));
      float mn = fmaxf(mrow[r], mx);
      float sc = __expf(mrow[r] - mn);
      mrow[r] = mn;
      float ls = 0.f;
      #pragma unroll
      for (int nf = 0; nf < 4; ++nf) {
        float p = __expf(sac[nf][r] - mn);
        sac[nf][r] = p;
        ls += p;
      }
      #pragma unroll
      for (int off = 1; off < 16; off <<= 1)
        ls += __shfl_xor(ls, off, 64);
      lrow[r] = lrow[r] * sc + ls;
      #pragma unroll
      for (int nf = 0; nf < 4; ++nf) oacc[nf][r] *= sc;
    }

    // ---- P -> bf16 LDS (overlays Pb; same-wave in-order DS) ----
    #pragma unroll
    for (int nf = 0; nf < 4; ++nf)
      #pragma unroll
      for (int r = 0; r < 4; ++r) {
        int row = (l >> 4) * 4 + r;
        int col = nf * 16 + (l & 15);
        pbs[row * 64 + (((col >> 3) ^ pkey(row)) << 3) + (col & 7)] = f2bf(sac[nf][r]);
      }

    // ---- PV from prefetched bv ----
    __builtin_amdgcn_s_setprio(1);
    #pragma unroll
    for (int kf = 0; kf < 2; ++kf) {
      int prow = l & 15;
      short8 ap = *(const short8*)&pbs[prow * 64 + (((kf * 4 + (l >> 4)) ^ pkey(prow)) << 3)];
      #pragma unroll
      for (int nf = 0; nf < 4; ++nf)
        oacc[nf] = __builtin_amdgcn_mfma_f32_16x16x32_bf16(ap, bv[kf][nf], oacc[nf], 0, 0, 0);
    }
    __builtin_amdgcn_s_setprio(0);
  }

  #pragma unroll
  for (int r = 0; r < 4; ++r) {
    float inv = 1.f / lrow[r];
    #pragma unroll
    for (int nf = 0; nf < 4; ++nf) {
      int row = i0 + (l >> 4) * 4 + r;
      int col = hh * 64 + nf * 16 + (l & 15);
      Ob[(size_t)(b * L_ + row) * D_ + col] = f2bf(oacc[nf][r] * inv);
    }
  }
}

// ---------------------------------------------------------------------------
// res = Ev + proj + Wo_b; LayerNorm * g + b. One block per row.
// ---------------------------------------------------------------------------
__global__ __launch_bounds__(256) void ln_kernel(
    const float* __restrict__ Ev, const float* __restrict__ proj,
    const float* __restrict__ Wo_b, const float* __restrict__ g,
    const float* __restrict__ beta, float* __restrict__ out) {
  const int row = blockIdx.x;
  __shared__ float red[8];
  const int tid = threadIdx.x;
  const int d = tid * 4;

  float4 e  = *(const float4*)&Ev[(size_t)row * D_ + d];
  float4 p  = *(const float4*)&proj[(size_t)row * D_ + d];
  float4 wb = *(const float4*)&Wo_b[d];
  float4 rr = { e.x + p.x + wb.x, e.y + p.y + wb.y,
                e.z + p.z + wb.z, e.w + p.w + wb.w };
  float sum = rr.x + rr.y + rr.z + rr.w;
  float sq  = rr.x * rr.x + rr.y * rr.y + rr.z * rr.z + rr.w * rr.w;

  #pragma unroll
  for (int off = 1; off < 64; off <<= 1) {
    sum += __shfl_xor(sum, off, 64);
    sq  += __shfl_xor(sq,  off, 64);
  }
  const int wid = tid >> 6;
  if ((tid & 63) == 0) { red[wid * 2] = sum; red[wid * 2 + 1] = sq; }
  __syncthreads();
  sum = red[0] + red[2] + red[4] + red[6];
  sq  = red[1] + red[3] + red[5] + red[7];

  const float mu   = sum * (1.f / (float)D_);
  const float var  = sq * (1.f / (float)D_) - mu * mu;
  const float rstd = rsqrtf(var + 1e-5f);

  float4 gg = *(const float4*)&g[d];
  float4 bb = *(const float4*)&beta[d];
  float4 o = { (rr.x - mu) * rstd * gg.x + bb.x,
               (rr.y - mu) * rstd * gg.y + bb.y,
               (rr.z - mu) * rstd * gg.z + bb.z,
               (rr.w - mu) * rstd * gg.w + bb.w };
  *(float4*)&out[(size_t)row * D_ + d] = o;
}

// ---------------------------------------------------------------------------
extern "C" void kernel_launch(void* const* d_in, const int* in_sizes, int n_in,
                              void* d_out, int out_size, void* d_ws, size_t ws_size,
                              hipStream_t stream) {
  const float* E    = (const float*)d_in[0];
  const float* Ev   = (const float*)d_in[1];
  const float* R    = (const float*)d_in[2];
  const float* Wq   = (const float*)d_in[3];
  const float* Wke  = (const float*)d_in[4];
  const float* Wkr  = (const float*)d_in[5];
  const float* Wv   = (const float*)d_in[6];
  const float* cb   = (const float*)d_in[7];
  const float* pb   = (const float*)d_in[8];
  const float* Wo_w = (const float*)d_in[9];
  const float* Wo_b = (const float*)d_in[10];
  const float* ln_g = (const float*)d_in[11];
  const float* ln_b = (const float*)d_in[12];
  float* out = (float*)d_out;

  // ws (shorts): Eb 2M | Evb 2M | Rb 1M | qb 2M | kb 2M | vt 2M | Qpb 1M |
  // Wt 5M | Ob 2M = 19M shorts = 38MB. proj fp32 overlays Eb+Evb (dead
  // after proj_g).
  short* ws   = (short*)d_ws;
  short* Eb   = ws;
  short* Evb  = ws + 2097152;
  short* Rb   = ws + 4194304;
  short* qb   = ws + 5242880;
  short* kb   = ws + 7340032;
  short* vt   = ws + 9437184;
  short* Qpb  = ws + 11534336;
  short* Wt   = ws + 12582912;
  short* Ob   = ws + 17825792;
  float* proj = (float*)Eb;

  // 1) prep: cast activations + transpose/cast weights
  prep<<<3840, 256, 0, stream>>>(E, Ev, R, Wq, Wke, Wkr, Wv, Wo_w, Eb, Wt);

  // 2) projections -> bf16 q, k, vt(transposed), Qp  (double-buffered glds)
  proj_g<<<dim3(16, 32, 4), 256, 0, stream>>>(Eb, Evb, Rb, Wt, qb, kb, vt, Qpb);

  // 3) attention -> bf16 O (barrier-free, register-prefetch pipeline)
  attn_d<<<2048, 64, 0, stream>>>(qb, kb, vt, Qpb, cb, pb, Ob);

  // 4) output projection -> fp32 proj
  out_g<<<dim3(16, 32), 256, 0, stream>>>(Ob, Wt + 4 * (size_t)D_ * D_, proj);

  // 5) residual + LayerNorm
  ln_kernel<<<B_ * L_, 256, 0, stream>>>(Ev, proj, Wo_b, ln_g, ln_b, out);
}

// Round 8
// 224.002 us; speedup vs baseline: 1.3388x; 1.0744x over previous
//
#include <hip/hip_runtime.h>
#include <hip/hip_bf16.h>
#include <math.h>

#define B_ 2
#define L_ 1024
#define D_ 1024
#define H_ 16

typedef short short8 __attribute__((ext_vector_type(8)));
typedef short short4v __attribute__((ext_vector_type(4)));
typedef float f32x4  __attribute__((ext_vector_type(4)));

__device__ __forceinline__ short f2bf(float f) {
  unsigned u = __float_as_uint(f);
  u += 0x7fff + ((u >> 16) & 1);          // RNE
  return (short)(u >> 16);
}
__device__ __forceinline__ float bf2f(short s) {
  return __uint_as_float(((unsigned)(unsigned short)s) << 16);
}
// XOR-swizzled LDS index (shorts) for [rows][64] bf16 tiles (16B slots).
__device__ __forceinline__ int swz(int row, int slot) {
  return row * 64 + (((slot ^ row) & 7) << 3);
}
// P-tile XOR key (wave-private P buffer bank spread)
__device__ __forceinline__ int pkey(int row) {
  return (row & 7) ^ ((row & 8) >> 2);
}
// global -> LDS direct (16B/lane; LDS dest = wave-uniform base + lane*16)
__device__ __forceinline__ void glds16(const void* g, void* l) {
  __builtin_amdgcn_global_load_lds((const __attribute__((address_space(1))) void*)g,
                                   (__attribute__((address_space(3))) void*)l, 16, 0, 0);
}

// ---------------------------------------------------------------------------
// prep: (a) cast E,Ev,R -> bf16 contiguous; (b) transpose+cast 5 weights.
// ---------------------------------------------------------------------------
__global__ __launch_bounds__(256) void prep(
    const float* __restrict__ E, const float* __restrict__ Ev,
    const float* __restrict__ R,
    const float* __restrict__ W0, const float* __restrict__ W1,
    const float* __restrict__ W2, const float* __restrict__ W3,
    const float* __restrict__ W4,
    short* __restrict__ act, short* __restrict__ Wt) {
  __shared__ short t[64][65];
  const int tid = threadIdx.x;
  int bid = blockIdx.x;
  if (bid < 2560) {
    size_t i8 = ((size_t)bid * 256 + tid) * 8;
    const float* src; size_t off;
    if (i8 < 2097152)      { src = E;  off = i8; }
    else if (i8 < 4194304) { src = Ev; off = i8 - 2097152; }
    else                   { src = R;  off = i8 - 4194304; }
    float4 a = *(const float4*)&src[off];
    float4 b = *(const float4*)&src[off + 4];
    short8 v;
    v[0] = f2bf(a.x); v[1] = f2bf(a.y); v[2] = f2bf(a.z); v[3] = f2bf(a.w);
    v[4] = f2bf(b.x); v[5] = f2bf(b.y); v[6] = f2bf(b.z); v[7] = f2bf(b.w);
    *(short8*)&act[i8] = v;
    return;
  }
  bid -= 2560;
  const int z = bid >> 8, rem = bid & 255;
  const int by = rem >> 4, bx = rem & 15;
  const float* W = (z == 0) ? W0 : (z == 1) ? W1 : (z == 2) ? W2 : (z == 3) ? W3 : W4;
  short* Wtz = Wt + (size_t)z * D_ * D_;
  const int r0 = by * 64, c0 = bx * 64;
  #pragma unroll
  for (int i = 0; i < 4; ++i) {
    int idx = tid + i * 256;
    int r = idx >> 4, c4 = (idx & 15) * 4;
    float4 v = *(const float4*)&W[(size_t)(r0 + r) * D_ + c0 + c4];
    t[c4 + 0][r] = f2bf(v.x); t[c4 + 1][r] = f2bf(v.y);
    t[c4 + 2][r] = f2bf(v.z); t[c4 + 3][r] = f2bf(v.w);
  }
  __syncthreads();
  #pragma unroll
  for (int i = 0; i < 2; ++i) {
    int idx = tid + i * 256;
    int rr = idx >> 3, cc = (idx & 7) * 8;
    short8 o;
    #pragma unroll
    for (int e = 0; e < 8; ++e) o[e] = t[rr][cc + e];
    *(short8*)&Wtz[(size_t)(c0 + rr) * D_ + r0 + cc] = o;
  }
}

// ---------------------------------------------------------------------------
// Double-buffered bf16 MFMA GEMM (R7-proven): C = A[M,1024] @ Bt[1024,1024]^T.
// Tile 64 x (NF*32), BK=64, 4 waves. STAGE(t+1) before COMPUTE(t); 1 barrier
// per K-step. OUT: 0 bf16, 1 f32, 2 bf16 per-head transposed vt.
// ---------------------------------------------------------------------------
template<int NF, int OUT>
__device__ __forceinline__ void mm_db(const short* __restrict__ A,
                                      const short* __restrict__ Bt,
                                      void* __restrict__ Cp,
                                      int bx, int by) {
  __shared__ short As0[4096], As1[4096];
  __shared__ short Bs0[NF * 2048], Bs1[NF * 2048];
  const int tid = threadIdx.x;
  const int l = tid & 63, w = tid >> 6;
  const int row0 = by * 64, col0 = bx * (NF * 32);
  const int wm = (w >> 1) * 32, wn = (w & 1) * (NF * 16);
  const int lr = l >> 3;
  const int lc = ((l & 7) ^ lr) * 8;     // inverse-swizzled source slot
  const f32x4 fz = {0.f, 0.f, 0.f, 0.f};

  f32x4 acc[2][NF];
  #pragma unroll
  for (int i = 0; i < 2; ++i)
    #pragma unroll
    for (int j = 0; j < NF; ++j) acc[i][j] = fz;

  auto STAGE = [&](short* AsD, short* BsD, int k0) {
    #pragma unroll
    for (int c = 0; c < 2; ++c) {
      int ch = w * 2 + c;
      glds16(&A[(size_t)(row0 + ch * 8 + lr) * 1024 + k0 + lc], &AsD[ch * 512]);
    }
    #pragma unroll
    for (int c = 0; c < NF; ++c) {
      int ch = w * NF + c;
      glds16(&Bt[(size_t)(col0 + ch * 8 + lr) * 1024 + k0 + lc], &BsD[ch * 512]);
    }
  };
  auto COMP = [&](const short* AsS, const short* BsS) {
    #pragma unroll
    for (int kf = 0; kf < 2; ++kf) {
      const int slot = kf * 4 + (l >> 4);
      short8 a[2], bfr[NF];
      #pragma unroll
      for (int mf = 0; mf < 2; ++mf)
        a[mf] = *(const short8*)&AsS[swz(wm + mf * 16 + (l & 15), slot)];
      #pragma unroll
      for (int nf = 0; nf < NF; ++nf)
        bfr[nf] = *(const short8*)&BsS[swz(wn + nf * 16 + (l & 15), slot)];
      #pragma unroll
      for (int mf = 0; mf < 2; ++mf)
        #pragma unroll
        for (int nf = 0; nf < NF; ++nf)
          acc[mf][nf] = __builtin_amdgcn_mfma_f32_16x16x32_bf16(a[mf], bfr[nf], acc[mf][nf], 0, 0, 0);
    }
  };

  STAGE(As0, Bs0, 0);
  __syncthreads();
  for (int t = 0; t < 16; t += 2) {
    if (t + 1 < 16) STAGE(As1, Bs1, (t + 1) * 64);
    COMP(As0, Bs0);
    __syncthreads();
    if (t + 2 < 16) STAGE(As0, Bs0, (t + 2) * 64);
    COMP(As1, Bs1);
    __syncthreads();
  }

  #pragma unroll
  for (int mf = 0; mf < 2; ++mf)
    #pragma unroll
    for (int nf = 0; nf < NF; ++nf) {
      if (OUT == 2) {
        int tok = row0 + wm + mf * 16 + (l >> 4) * 4;
        int col = col0 + wn + nf * 16 + (l & 15);
        int bb = tok >> 10, j = tok & 1023;
        int h = col >> 6, d = col & 63;
        short4v o;
        #pragma unroll
        for (int r = 0; r < 4; ++r) o[r] = f2bf(acc[mf][nf][r]);
        *(short4v*)&((short*)Cp)[((size_t)((bb * H_ + h) * 64 + d)) * 1024 + j] = o;
      } else {
        #pragma unroll
        for (int r = 0; r < 4; ++r) {
          int row = row0 + wm + mf * 16 + (l >> 4) * 4 + r;
          int col = col0 + wn + nf * 16 + (l & 15);
          if (OUT == 1) ((float*)Cp)[(size_t)row * 1024 + col] = acc[mf][nf][r];
          else          ((short*)Cp)[(size_t)row * 1024 + col] = f2bf(acc[mf][nf][r]);
        }
      }
    }
}

// z=0: q=Eb@Wq ; z=1: k=Evb@Wke ; z=2: vt=(Evb@Wv)^T ; z=3: Qp=Rb@Wkr.
__global__ __launch_bounds__(256) void proj_g(
    const short* __restrict__ Eb, const short* __restrict__ Evb,
    const short* __restrict__ Rb, const short* __restrict__ Wt,
    short* __restrict__ qb, short* __restrict__ kb,
    short* __restrict__ vt, short* __restrict__ Qpb) {
  const int z = blockIdx.z;
  const size_t MM = (size_t)D_ * D_;
  const short* A; const short* Bt; short* C; int M;
  if (z == 0)      { A = Eb;  Bt = Wt;          C = qb;  M = B_ * L_; }
  else if (z == 1) { A = Evb; Bt = Wt + MM;     C = kb;  M = B_ * L_; }
  else if (z == 2) { A = Evb; Bt = Wt + 3 * MM; C = vt;  M = B_ * L_; }
  else             { A = Rb;  Bt = Wt + 2 * MM; C = Qpb; M = L_;      }
  if ((int)blockIdx.y * 64 >= M) return;
  if (z == 2) mm_db<4, 2>(A, Bt, C, blockIdx.x, blockIdx.y);
  else        mm_db<4, 0>(A, Bt, C, blockIdx.x, blockIdx.y);
}

__global__ __launch_bounds__(256) void out_g(
    const short* __restrict__ Ob, const short* __restrict__ Wot,
    float* __restrict__ proj) {
  mm_db<2, 1>(Ob, Wot, proj, blockIdx.x, blockIdx.y);
}

// ---------------------------------------------------------------------------
// MFMA attention (R4 structure, de-VALU'd). Block = 64 q-rows of one (b,h),
// 4 waves x 16-row strips. K and V^T double-buffer-staged via glds16 (1
// barrier/tile, stage-before-compute). Window Qp: per-wave register prefetch
// one tile ahead. Biases folded into A-frags: S = (q+cb).k + (q+pb).Qp[m].
// ---------------------------------------------------------------------------
__global__ __launch_bounds__(256, 3) void attn_s(
    const short* __restrict__ qb, const short* __restrict__ kb,
    const short* __restrict__ vt, const short* __restrict__ Qpb,
    const float* __restrict__ cb, const float* __restrict__ pb,
    short* __restrict__ Ob) {
  __shared__ short k_s0[4096], k_s1[4096];
  __shared__ short vt_s0[4096], vt_s1[4096];
  __shared__ short pbs[4 * 1312];   // per-wave Pb[16][82] | P[16][64]

  const int tid = threadIdx.x;
  const int l = tid & 63, w = tid >> 6;
  const int hl = blockIdx.x & 31;        // (b,h) fastest -> XCD L2 locality
  const int it = blockIdx.x >> 5;        // 0..15
  const int b = hl >> 4, hh = hl & 15;
  const int i0 = it * 64;
  const int i0w = i0 + w * 16;           // this wave's first q row
  const f32x4 fz = {0.f, 0.f, 0.f, 0.f};

  const int lr = l >> 3;
  const int lc = ((l & 7) ^ lr) * 8;     // inverse-swizzled source slot

  // ---- A-fragments with folded biases ----
  short8 aqc[2], aqp[2];
  {
    const size_t qoff = (size_t)(b * L_ + i0w + (l & 15)) * D_ + hh * 64 + (l >> 4) * 8;
    #pragma unroll
    for (int kf = 0; kf < 2; ++kf) {
      short8 qv = *(const short8*)&qb[qoff + kf * 32];
      const float* cbp = &cb[hh * 64 + kf * 32 + (l >> 4) * 8];
      const float* pbp = &pb[hh * 64 + kf * 32 + (l >> 4) * 8];
      #pragma unroll
      for (int e = 0; e < 8; ++e) {
        float q = bf2f(qv[e]);
        aqc[kf][e] = f2bf(q + cbp[e]);
        aqp[kf][e] = f2bf(q + pbp[e]);
      }
    }
  }

  const short* kbase  = &kb[(size_t)(b * L_) * D_ + hh * 64];
  const short* vtbase = &vt[(size_t)((b * H_ + hh) * 64) * 1024];
  const short* wbase  = &Qpb[hh * 64 + (l >> 4) * 8];

  // K/V^T staging: 8 chunks of 8 rows each; wave w does chunks {2w, 2w+1}.
  auto STAGE = [&](short* kD, short* vD, int jt) {
    const int j0 = jt * 64;
    #pragma unroll
    for (int c = 0; c < 2; ++c) {
      int ch = w * 2 + c;
      glds16(&kbase[(size_t)(j0 + ch * 8 + lr) * D_ + lc], &kD[ch * 512]);
      glds16(&vtbase[(size_t)(ch * 8 + lr) * 1024 + j0 + lc], &vD[ch * 512]);
    }
  };

  // window prefetch (per-wave, direct global -> regs, one tile ahead)
  short8 bw[2][5];
  auto LW = [&](int jt) {
    const int mb = L_ - 16 - (i0w - jt * 64);
    #pragma unroll
    for (int kf = 0; kf < 2; ++kf)
      #pragma unroll
      for (int u = 0; u < 5; ++u) {
        int m = mb + u * 16 + (l & 15);
        m = (m < L_) ? m : (L_ - 1);     // clamped rows masked in gather
        bw[kf][u] = *(const short8*)&wbase[(size_t)m * D_ + kf * 32];
      }
  };

  STAGE(k_s0, vt_s0, 0);
  LW(0);                                 // jt=0: all waves pos (i0w >= 0)
  __syncthreads();

  float mrow[4], lrow[4];
  f32x4 oacc[4];
  #pragma unroll
  for (int r = 0; r < 4; ++r) { mrow[r] = -3.0e38f; lrow[r] = 0.f; }
  #pragma unroll
  for (int nf = 0; nf < 4; ++nf) oacc[nf] = fz;

  const int pbb = w * 1312;

  for (int jt = 0; jt < 16; ++jt) {
    const int dth = i0w - jt * 64;       // j<=i  <=>  rj <= ris + dth
    const bool pos = (dth >= -15);
    const short* kS  = (jt & 1) ? k_s1 : k_s0;
    const short* vS  = (jt & 1) ? vt_s1 : vt_s0;
    short* kD = (jt & 1) ? k_s0 : k_s1;
    short* vD = (jt & 1) ? vt_s0 : vt_s1;

    if (jt < 15) STAGE(kD, vD, jt + 1);  // flies under this tile's compute

    // ---- QK^T ----
    f32x4 sac[4];
    #pragma unroll
    for (int nf = 0; nf < 4; ++nf) sac[nf] = fz;
    __builtin_amdgcn_s_setprio(1);
    #pragma unroll
    for (int kf = 0; kf < 2; ++kf) {
      const int slot = kf * 4 + (l >> 4);
      #pragma unroll
      for (int nf = 0; nf < 4; ++nf) {
        short8 bk = *(const short8*)&kS[swz(nf * 16 + (l & 15), slot)];
        sac[nf] = __builtin_amdgcn_mfma_f32_16x16x32_bf16(aqc[kf], bk, sac[nf], 0, 0, 0);
      }
    }
    __builtin_amdgcn_s_setprio(0);

    if (pos) {
      // ---- positional GEMM from prefetched bw ----
      f32x4 pacc[5];
      #pragma unroll
      for (int u = 0; u < 5; ++u) pacc[u] = fz;
      __builtin_amdgcn_s_setprio(1);
      #pragma unroll
      for (int kf = 0; kf < 2; ++kf)
        #pragma unroll
        for (int u = 0; u < 5; ++u)
          pacc[u] = __builtin_amdgcn_mfma_f32_16x16x32_bf16(aqp[kf], bw[kf][u], pacc[u], 0, 0, 0);
      __builtin_amdgcn_s_setprio(0);
      #pragma unroll
      for (int u = 0; u < 5; ++u)
        #pragma unroll
        for (int r = 0; r < 4; ++r) {
          int row = (l >> 4) * 4 + r;
          pbs[pbb + row * 82 + u * 16 + (l & 15)] = f2bf(pacc[u][r]);
        }
    }

    // prefetch next tile's window (bw dead after pos MFMAs above)
    if (jt < 15 && dth - 64 >= -15) LW(jt + 1);

    if (pos) {
      // shifted gather: S[ris][rj] += Pb[ris][15-ris+rj] where j<=i
      #pragma unroll
      for (int nf = 0; nf < 4; ++nf)
        #pragma unroll
        for (int r = 0; r < 4; ++r) {
          int ris = (l >> 4) * 4 + r;
          int rj = nf * 16 + (l & 15);
          if (rj <= ris + dth)
            sac[nf][r] += bf2f(pbs[pbb + ris * 82 + (15 - ris + rj)]);
        }
    }

    // ---- online softmax (16-lane row groups) ----
    #pragma unroll
    for (int r = 0; r < 4; ++r) {
      float mx = fmaxf(fmaxf(sac[0][r], sac[1][r]), fmaxf(sac[2][r], sac[3][r]));
      #pragma unroll
      for (int off = 1; off < 16; off <<= 1)
        mx = fmaxf(mx, __shfl_xor(mx, off, 64));
      float mn = fmaxf(mrow[r], mx);
      float sc = __expf(mrow[r] - mn);
      mrow[r] = mn;
      float ls = 0.f;
      #pragma unroll
      for (int nf = 0; nf < 4; ++nf) {
        float p = __expf(sac[nf][r] - mn);
        sac[nf][r] = p;
        ls += p;
      }
      #pragma unroll
      for (int off = 1; off < 16; off <<= 1)
        ls += __shfl_xor(ls, off, 64);
      lrow[r] = lrow[r] * sc + ls;
      #pragma unroll
      for (int nf = 0; nf < 4; ++nf) oacc[nf][r] *= sc;
    }

    // ---- P -> bf16, wave-private LDS ----
    #pragma unroll
    for (int nf = 0; nf < 4; ++nf)
      #pragma unroll
      for (int r = 0; r < 4; ++r) {
        int row = (l >> 4) * 4 + r;
        int col = nf * 16 + (l & 15);
        pbs[pbb + row * 64 + (((col >> 3) ^ pkey(row)) << 3) + (col & 7)] = f2bf(sac[nf][r]);
      }

    // ---- PV from staged V^T ----
    __builtin_amdgcn_s_setprio(1);
    #pragma unroll
    for (int kf = 0; kf < 2; ++kf) {
      int prow = l & 15;
      short8 ap = *(const short8*)&pbs[pbb + prow * 64 + (((kf * 4 + (l >> 4)) ^ pkey(prow)) << 3)];
      #pragma unroll
      for (int nf = 0; nf < 4; ++nf) {
        short8 bv = *(const short8*)&vS[swz(nf * 16 + (l & 15), kf * 4 + (l >> 4))];
        oacc[nf] = __builtin_amdgcn_mfma_f32_16x16x32_bf16(ap, bv, oacc[nf], 0, 0, 0);
      }
    }
    __builtin_amdgcn_s_setprio(0);

    __syncthreads();   // next-tile stage complete; this tile's LDS free
  }

  #pragma unroll
  for (int r = 0; r < 4; ++r) {
    float inv = 1.f / lrow[r];
    #pragma unroll
    for (int nf = 0; nf < 4; ++nf) {
      int row = i0w + (l >> 4) * 4 + r;
      int col = hh * 64 + nf * 16 + (l & 15);
      Ob[(size_t)(b * L_ + row) * D_ + col] = f2bf(oacc[nf][r] * inv);
    }
  }
}

// ---------------------------------------------------------------------------
// res = Ev + proj + Wo_b; LayerNorm * g + b. One block per row.
// ---------------------------------------------------------------------------
__global__ __launch_bounds__(256) void ln_kernel(
    const float* __restrict__ Ev, const float* __restrict__ proj,
    const float* __restrict__ Wo_b, const float* __restrict__ g,
    const float* __restrict__ beta, float* __restrict__ out) {
  const int row = blockIdx.x;
  __shared__ float red[8];
  const int tid = threadIdx.x;
  const int d = tid * 4;

  float4 e  = *(const float4*)&Ev[(size_t)row * D_ + d];
  float4 p  = *(const float4*)&proj[(size_t)row * D_ + d];
  float4 wb = *(const float4*)&Wo_b[d];
  float4 rr = { e.x + p.x + wb.x, e.y + p.y + wb.y,
                e.z + p.z + wb.z, e.w + p.w + wb.w };
  float sum = rr.x + rr.y + rr.z + rr.w;
  float sq  = rr.x * rr.x + rr.y * rr.y + rr.z * rr.z + rr.w * rr.w;

  #pragma unroll
  for (int off = 1; off < 64; off <<= 1) {
    sum += __shfl_xor(sum, off, 64);
    sq  += __shfl_xor(sq,  off, 64);
  }
  const int wid = tid >> 6;
  if ((tid & 63) == 0) { red[wid * 2] = sum; red[wid * 2 + 1] = sq; }
  __syncthreads();
  sum = red[0] + red[2] + red[4] + red[6];
  sq  = red[1] + red[3] + red[5] + red[7];

  const float mu   = sum * (1.f / (float)D_);
  const float var  = sq * (1.f / (float)D_) - mu * mu;
  const float rstd = rsqrtf(var + 1e-5f);

  float4 gg = *(const float4*)&g[d];
  float4 bb = *(const float4*)&beta[d];
  float4 o = { (rr.x - mu) * rstd * gg.x + bb.x,
               (rr.y - mu) * rstd * gg.y + bb.y,
               (rr.z - mu) * rstd * gg.z + bb.z,
               (rr.w - mu) * rstd * gg.w + bb.w };
  *(float4*)&out[(size_t)row * D_ + d] = o;
}

// ---------------------------------------------------------------------------
extern "C" void kernel_launch(void* const* d_in, const int* in_sizes, int n_in,
                              void* d_out, int out_size, void* d_ws, size_t ws_size,
                              hipStream_t stream) {
  const float* E    = (const float*)d_in[0];
  const float* Ev   = (const float*)d_in[1];
  const float* R    = (const float*)d_in[2];
  const float* Wq   = (const float*)d_in[3];
  const float* Wke  = (const float*)d_in[4];
  const float* Wkr  = (const float*)d_in[5];
  const float* Wv   = (const float*)d_in[6];
  const float* cb   = (const float*)d_in[7];
  const float* pb   = (const float*)d_in[8];
  const float* Wo_w = (const float*)d_in[9];
  const float* Wo_b = (const float*)d_in[10];
  const float* ln_g = (const float*)d_in[11];
  const float* ln_b = (const float*)d_in[12];
  float* out = (float*)d_out;

  // ws (shorts): Eb 2M | Evb 2M | Rb 1M | qb 2M | kb 2M | vt 2M | Qpb 1M |
  // Wt 5M | Ob 2M = 19M shorts = 38MB. proj fp32 overlays Eb+Evb.
  short* ws   = (short*)d_ws;
  short* Eb   = ws;
  short* Evb  = ws + 2097152;
  short* Rb   = ws + 4194304;
  short* qb   = ws + 5242880;
  short* kb   = ws + 7340032;
  short* vt   = ws + 9437184;
  short* Qpb  = ws + 11534336;
  short* Wt   = ws + 12582912;
  short* Ob   = ws + 17825792;
  float* proj = (float*)Eb;

  // 1) prep: cast activations + transpose/cast weights
  prep<<<3840, 256, 0, stream>>>(E, Ev, R, Wq, Wke, Wkr, Wv, Wo_w, Eb, Wt);

  // 2) projections -> bf16 q, k, vt(transposed), Qp  (64x128 dbuf tiles)
  proj_g<<<dim3(8, 32, 4), 256, 0, stream>>>(Eb, Evb, Rb, Wt, qb, kb, vt, Qpb);

  // 3) attention -> bf16 O (4-wave LDS-staged, bias-folded, dbuf glds)
  attn_s<<<512, 256, 0, stream>>>(qb, kb, vt, Qpb, cb, pb, Ob);

  // 4) output projection -> fp32 proj
  out_g<<<dim3(16, 32), 256, 0, stream>>>(Ob, Wt + 4 * (size_t)D_ * D_, proj);

  // 5) residual + LayerNorm
  ln_kernel<<<B_ * L_, 256, 0, stream>>>(Ev, proj, Wo_b, ln_g, ln_b, out);
}